// Round 5
// baseline (259.570 us; speedup 1.0000x reference)
//
#include <hip/hip_runtime.h>

typedef __bf16 bf16;
typedef __bf16 bf16x8 __attribute__((ext_vector_type(8)));
typedef __bf16 bf16x4 __attribute__((ext_vector_type(4)));
typedef float f32x4 __attribute__((ext_vector_type(4)));

static __device__ __forceinline__ bf16x8 ld8(const bf16* p) {
    return *reinterpret_cast<const bf16x8*>(p);
}
static __device__ __forceinline__ bf16x4 ld4(const bf16* p) {
    return *reinterpret_cast<const bf16x4*>(p);
}
// 8-elem load from 8B-aligned (not necessarily 16B-aligned) LDS address
static __device__ __forceinline__ bf16x8 ld8u(const bf16* p) {
    bf16x4 lo = *reinterpret_cast<const bf16x4*>(p);
    bf16x4 hi = *reinterpret_cast<const bf16x4*>(p + 4);
    bf16x8 v;
#pragma unroll
    for (int i = 0; i < 4; ++i) { v[i] = lo[i]; v[i + 4] = hi[i]; }
    return v;
}
static __device__ __forceinline__ bf16x8 zero8() {
    bf16x8 v;
#pragma unroll
    for (int i = 0; i < 8; ++i) v[i] = (bf16)0.f;
    return v;
}

#define MFMA16(a, b, c) __builtin_amdgcn_mfma_f32_16x16x32_bf16((a), (b), (c), 0, 0, 0)

// ---------------------------------------------------------------------------
// prep: weight fp32->bf16 conversion with pad/scatter, plus bias table gather.
//   wkv  [384][192], wq [256][192], wproj [256][192] (head-padded K),
//   wfc1 [768][192], wfc2 [256][736]
//   biast[h][q(256)][key(576)] bf16 = rpb[rpi[q][key]][h]   (key contiguous)
// ---------------------------------------------------------------------------
__global__ __launch_bounds__(256) void prep_kernel(
    const float* __restrict__ kv_w, const float* __restrict__ q_w,
    const float* __restrict__ proj_w, const float* __restrict__ fc1_w,
    const float* __restrict__ fc2_w, const float* __restrict__ rpb,
    const int* __restrict__ rpi,
    bf16* __restrict__ wkv, bf16* __restrict__ wq, bf16* __restrict__ wproj,
    bf16* __restrict__ wfc1, bf16* __restrict__ wfc2, bf16* __restrict__ biast)
{
    int i = blockIdx.x * 256 + threadIdx.x;
    if (i < 73728) {                       // wkv
        int n = i / 192, k = i % 192;
        float v = (n < 360 && k < 180) ? kv_w[n * 180 + k] : 0.f;
        wkv[i] = (bf16)v;
    } else if (i < 122880) {               // wq
        int j = i - 73728; int n = j / 192, k = j % 192;
        float v = (n < 180 && k < 180) ? q_w[n * 180 + k] : 0.f;
        wq[j] = (bf16)v;
    } else if (i < 172032) {               // wproj (head-padded K)
        int j = i - 122880; int n = j / 192, k = j % 192;
        int hh = k >> 5, d = k & 31;
        float v = (n < 180 && d < 30) ? proj_w[n * 180 + hh * 30 + d] : 0.f;
        wproj[j] = (bf16)v;
    } else if (i < 319488) {               // wfc1
        int j = i - 172032; int n = j / 192, k = j % 192;
        float v = (n < 720 && k < 180) ? fc1_w[n * 180 + k] : 0.f;
        wfc1[j] = (bf16)v;
    } else if (i < 507904) {               // wfc2
        int j = i - 319488; int n = j / 736, k = j % 736;
        float v = (n < 180 && k < 720) ? fc2_w[n * 720 + k] : 0.f;
        wfc2[j] = (bf16)v;
    } else if (i < 1392640) {              // bias table [h][q][key]
        int t = i - 507904;
        int h = t / 147456, rem = t % 147456;
        int q = rem / 576, key = rem % 576;
        biast[t] = (bf16)rpb[rpi[q * 576 + key] * 6 + h];
    }
}

// ---------------------------------------------------------------------------
// LayerNorm: one wave per row of 180 fp32 -> bf16 [row][192] (tail zeroed).
// ---------------------------------------------------------------------------
__global__ __launch_bounds__(256) void ln_kernel(
    const float* __restrict__ srcA, const float* __restrict__ srcB,
    const float* __restrict__ g, const float* __restrict__ b,
    bf16* __restrict__ dst)
{
    int wave = threadIdx.x >> 6, lane = threadIdx.x & 63;
    int row = blockIdx.x * 4 + wave;
    const float* sp = (row < 16384) ? (srcA + row * 180) : (srcB + (row - 16384) * 180);
    float v0 = sp[lane];
    float v1 = sp[lane + 64];
    float v2 = (lane < 52) ? sp[lane + 128] : 0.f;
    float s = v0 + v1 + v2;
    float sq = v0 * v0 + v1 * v1 + v2 * v2;
#pragma unroll
    for (int m = 32; m >= 1; m >>= 1) {
        s += __shfl_xor(s, m);
        sq += __shfl_xor(sq, m);
    }
    float mean = s * (1.f / 180.f);
    float var = sq * (1.f / 180.f) - mean * mean;
    float rs = rsqrtf(var + 1e-5f);
    bf16* dp = dst + (long)row * 192;
    dp[lane] = (bf16)((v0 - mean) * rs * g[lane] + b[lane]);
    dp[lane + 64] = (bf16)((v1 - mean) * rs * g[lane + 64] + b[lane + 64]);
    float o2 = (lane < 52) ? ((v2 - mean) * rs * g[lane + 128] + b[lane + 128]) : 0.f;
    dp[lane + 128] = (bf16)o2;
}

// ---------------------------------------------------------------------------
// kv+q projection GEMM, occupancy-tuned: wave tile 32x64, waves M-stacked.
// grid = (16384/128, 9): ng 0..5 -> kv cols (N=384), ng 6..8 -> q cols (N=192).
// ---------------------------------------------------------------------------
__global__ __launch_bounds__(256, 4) void gemm_kvq(
    const bf16* __restrict__ xn, const bf16* __restrict__ yn,
    const bf16* __restrict__ wkv, const bf16* __restrict__ wq,
    const float* __restrict__ kv_b, const float* __restrict__ q_b,
    bf16* __restrict__ kvbuf, bf16* __restrict__ qbuf)
{
    const int tid = threadIdx.x, wave = tid >> 6, lane = tid & 63;
    const int llo = lane & 15, quad = lane >> 4;
    const int ng = blockIdx.y;
    const bool isq = ng >= 6;
    const bf16* A = isq ? yn : xn;
    const bf16* W = isq ? (wq + (ng - 6) * 64 * 192) : (wkv + ng * 64 * 192);
    const int mbase = blockIdx.x * 128 + wave * 32;

    f32x4 acc[2][4];
#pragma unroll
    for (int mt = 0; mt < 2; ++mt)
#pragma unroll
        for (int nt = 0; nt < 4; ++nt)
#pragma unroll
            for (int r = 0; r < 4; ++r) acc[mt][nt][r] = 0.f;

    for (int kt = 0; kt < 6; ++kt) {
        bf16x8 a[2], b[4];
#pragma unroll
        for (int mt = 0; mt < 2; ++mt)
            a[mt] = ld8(A + (long)(mbase + mt * 16 + llo) * 192 + kt * 32 + quad * 8);
#pragma unroll
        for (int nt = 0; nt < 4; ++nt)
            b[nt] = ld8(W + (long)(nt * 16 + llo) * 192 + kt * 32 + quad * 8);
#pragma unroll
        for (int mt = 0; mt < 2; ++mt)
#pragma unroll
            for (int nt = 0; nt < 4; ++nt)
                acc[mt][nt] = MFMA16(a[mt], b[nt], acc[mt][nt]);
    }

#pragma unroll
    for (int mt = 0; mt < 2; ++mt)
#pragma unroll
        for (int nt = 0; nt < 4; ++nt)
#pragma unroll
            for (int r = 0; r < 4; ++r) {
                int m = mbase + mt * 16 + quad * 4 + r;
                int n = ng * 64 + nt * 16 + llo;
                if (!isq) {
                    if (n < 360) {
                        float v = acc[mt][nt][r] + kv_b[n];
                        int nn = n % 180;
                        int col = (n / 180) * 192 + (nn / 30) * 32 + (nn % 30);
                        kvbuf[(long)m * 384 + col] = (bf16)v;
                    }
                } else {
                    int nq = n - 384;
                    if (nq < 180) {
                        float v = (acc[mt][nt][r] + q_b[nq]) * 0.18257418583505537f;
                        int col = (nq / 30) * 32 + (nq % 30);
                        qbuf[(long)m * 192 + col] = (bf16)v;
                    }
                }
            }
}

// ---------------------------------------------------------------------------
// Attention v5: v4 + Vt stride 76 (kills the structural 4-way bank conflict
// on the transpose store: 8 rows x 38 banks = 16 mod 32, vs 0 for stride 72).
// Vt reads switch to b64 pairs (stride 152 B is 8B-aligned, not 16B).
// ---------------------------------------------------------------------------
__global__ __launch_bounds__(512, 6) void attn_kernel(
    const bf16* __restrict__ qbuf,   // [16384][192] head-padded, pre-scaled
    const bf16* __restrict__ kvbuf,  // [16384][384] K at +0, V at +192
    const bf16* __restrict__ biast,  // [6][256][576]
    bf16* __restrict__ obuf)         // [16384][192] head-padded
{
    const int qhalf = blockIdx.x & 1;
    const int head = (blockIdx.x >> 1) % 6;
    const int win = blockIdx.x / 12;
    const int bb = win / 16, wi = (win % 16) / 4, wj = win % 4;
    const int tid = threadIdx.x;
    const int wave = tid >> 6, lane = tid & 63;
    const int llo = lane & 15, quad = lane >> 4;
    const int qbase = qhalf * 128 + wave * 16;

    __shared__ bf16 Kc[64][40];        // K chunk: [key][d], b128-stored
    __shared__ bf16 Vt[32][76];        // V chunk transposed: [d][key], pad 76
    __shared__ bf16 Ps[8][16][72];     // per-wave P: [query][key]

    const int u = tid & 255;
    const int tloc = u >> 2, dq = u & 3;
    const bool isV = tid >= 256;
    int aa = tloc / 24, w0 = tloc % 24;   // key = c*64 + tloc decomposed

    const int q0 = qbase + llo;
    const int gr_q = bb * 4096 + (wi * 16 + (q0 >> 4)) * 64 + (wj * 16 + (q0 & 15));
    const bf16x8 qf = ld8(qbuf + (long)gr_q * 192 + head * 32 + quad * 8);

    f32x4 o[2];
    float m_run = -1e30f, l_run = 0.f;
#pragma unroll
    for (int n2 = 0; n2 < 2; ++n2)
#pragma unroll
        for (int r = 0; r < 4; ++r) o[n2][r] = 0.f;

    for (int c = 0; c < 9; ++c) {
        const int kb = c * 64;
        __syncthreads();               // prior chunk's LDS reads done
        {   // stage K (tid<256) / V (tid>=256)
            int gy = wi * 16 + aa - 4, gx = wj * 16 + w0 - 4;
            bf16x8 v = zero8();
            if ((unsigned)gy < 64u && (unsigned)gx < 64u) {
                long gr = (long)(bb * 4096 + gy * 64 + gx) * 384;
                v = ld8(kvbuf + gr + (isV ? 192 : 0) + head * 32 + dq * 8);
            }
            if (!isV) {
                *reinterpret_cast<bf16x8*>(&Kc[tloc][dq * 8]) = v;
            } else {
#pragma unroll
                for (int j = 0; j < 8; ++j) Vt[dq * 8 + j][tloc] = v[j];
            }
            w0 += 16; aa += 2;
            if (w0 >= 24) { w0 -= 24; ++aa; }
        }
        __syncthreads();               // Kc/Vt ready

        // ---- S^T = K·Q^T  (A = Kc[key][d], B = qf) ----
        f32x4 s[4];
#pragma unroll
        for (int kt = 0; kt < 4; ++kt) {
            bf16x8 kf = ld8(&Kc[kt * 16 + llo][quad * 8]);
            f32x4 zc;
            zc[0] = 0.f; zc[1] = 0.f; zc[2] = 0.f; zc[3] = 0.f;
            s[kt] = MFMA16(kf, qf, zc);
        }

        // ---- + bias ----
#pragma unroll
        for (int kt = 0; kt < 4; ++kt) {
            bf16x4 bv = ld4(biast + ((long)head * 256 + q0) * 576 + kb + kt * 16 + quad * 4);
#pragma unroll
            for (int r = 0; r < 4; ++r) s[kt][r] += (float)bv[r];
        }

        // ---- online softmax (keys in-lane + quad shuffles) ----
        float mx = s[0][0];
#pragma unroll
        for (int kt = 0; kt < 4; ++kt)
#pragma unroll
            for (int r = 0; r < 4; ++r) mx = fmaxf(mx, s[kt][r]);
        mx = fmaxf(mx, __shfl_xor(mx, 16));
        mx = fmaxf(mx, __shfl_xor(mx, 32));
        float m_new = fmaxf(m_run, mx);
        float alpha = __expf(m_run - m_new);
        float ls = 0.f;
#pragma unroll
        for (int kt = 0; kt < 4; ++kt)
#pragma unroll
            for (int r = 0; r < 4; ++r) {
                float p = __expf(s[kt][r] - m_new);
                s[kt][r] = p;
                ls += p;
            }
        ls += __shfl_xor(ls, 16);
        ls += __shfl_xor(ls, 32);
        l_run = l_run * alpha + ls;
        m_run = m_new;

#pragma unroll
        for (int r = 0; r < 4; ++r) {
            float a = __shfl(alpha, quad * 4 + r);
            o[0][r] *= a;
            o[1][r] *= a;
        }

        // ---- pack P -> LDS [query][key] (b64 stores, wave-private) ----
#pragma unroll
        for (int kt = 0; kt < 4; ++kt) {
            bf16x4 pv;
#pragma unroll
            for (int r = 0; r < 4; ++r) pv[r] = (bf16)s[kt][r];
            *reinterpret_cast<bf16x4*>(&Ps[wave][llo][kt * 16 + quad * 4]) = pv;
        }

        // ---- O += P·V  (A = Ps[query][key], B = Vt[d][key]) ----
#pragma unroll
        for (int kt2 = 0; kt2 < 2; ++kt2) {
            bf16x8 pa = ld8(&Ps[wave][llo][kt2 * 32 + quad * 8]);
#pragma unroll
            for (int n2 = 0; n2 < 2; ++n2) {
                bf16x8 vb = ld8u(&Vt[n2 * 16 + llo][kt2 * 32 + quad * 8]);
                o[n2] = MFMA16(pa, vb, o[n2]);
            }
        }
    }

    // ---- normalize and write out ----
    float linv = 1.f / l_run;
#pragma unroll
    for (int r = 0; r < 4; ++r) {
        float li = __shfl(linv, quad * 4 + r);
        int q = qbase + quad * 4 + r;
        int gr = bb * 4096 + (wi * 16 + (q >> 4)) * 64 + (wj * 16 + (q & 15));
#pragma unroll
        for (int n2 = 0; n2 < 2; ++n2)
            obuf[(long)gr * 192 + head * 32 + n2 * 16 + llo] = (bf16)(o[n2][r] * li);
    }
}

// ---------------------------------------------------------------------------
// Epilogue GEMM v2: wave tile (MT*16) x 64, 4 waves M-stacked per block.
// grid = (16384/(MT*64), N/64). MODE 2: fp32 out = v + resid; MODE 3: gelu bf16.
// ---------------------------------------------------------------------------
template <int MT, int MINW, int KPAD, int NREAL, int OSTRIDE, int MODE>
__global__ __launch_bounds__(256, MINW) void gemm_ep(
    const bf16* __restrict__ A, const bf16* __restrict__ W,
    const float* __restrict__ bias, const float* __restrict__ resid,
    void* __restrict__ outp)
{
    const int tid = threadIdx.x, wave = tid >> 6, lane = tid & 63;
    const int llo = lane & 15, quad = lane >> 4;
    const int mbase = blockIdx.x * (MT * 64) + wave * (MT * 16);
    const int nbase = blockIdx.y * 64;

    f32x4 acc[MT][4];
#pragma unroll
    for (int mt = 0; mt < MT; ++mt)
#pragma unroll
        for (int nt = 0; nt < 4; ++nt)
#pragma unroll
            for (int r = 0; r < 4; ++r) acc[mt][nt][r] = 0.f;

    for (int kt = 0; kt < KPAD / 32; ++kt) {
        bf16x8 a[MT], b[4];
#pragma unroll
        for (int mt = 0; mt < MT; ++mt)
            a[mt] = ld8(A + (long)(mbase + mt * 16 + llo) * KPAD + kt * 32 + quad * 8);
#pragma unroll
        for (int nt = 0; nt < 4; ++nt)
            b[nt] = ld8(W + (long)(nbase + nt * 16 + llo) * KPAD + kt * 32 + quad * 8);
#pragma unroll
        for (int mt = 0; mt < MT; ++mt)
#pragma unroll
            for (int nt = 0; nt < 4; ++nt)
                acc[mt][nt] = MFMA16(a[mt], b[nt], acc[mt][nt]);
    }

#pragma unroll
    for (int mt = 0; mt < MT; ++mt)
#pragma unroll
        for (int nt = 0; nt < 4; ++nt)
#pragma unroll
            for (int r = 0; r < 4; ++r) {
                int m = mbase + mt * 16 + quad * 4 + r;
                int n = nbase + nt * 16 + llo;
                if (n >= NREAL) continue;
                float v = acc[mt][nt][r] + bias[n];
                if (MODE == 2) {
                    ((float*)outp)[(long)m * OSTRIDE + n] = v + resid[(long)m * 180 + n];
                } else {
                    float gel = 0.5f * v * (1.f + erff(v * 0.7071067811865475f));
                    ((bf16*)outp)[(long)m * OSTRIDE + n] = (bf16)gel;
                }
            }
}

// ---------------------------------------------------------------------------
extern "C" void kernel_launch(void* const* d_in, const int* in_sizes, int n_in,
                              void* d_out, int out_size, void* d_ws, size_t ws_size,
                              hipStream_t stream) {
    const float* x      = (const float*)d_in[0];
    const float* y      = (const float*)d_in[1];
    const float* n1g    = (const float*)d_in[2];
    const float* n1b    = (const float*)d_in[3];
    const float* kv_w   = (const float*)d_in[4];
    const float* kv_b   = (const float*)d_in[5];
    const float* q_w    = (const float*)d_in[6];
    const float* q_b    = (const float*)d_in[7];
    const float* rpb    = (const float*)d_in[8];
    const float* proj_w = (const float*)d_in[9];
    const float* proj_b = (const float*)d_in[10];
    const float* n2g    = (const float*)d_in[11];
    const float* n2b    = (const float*)d_in[12];
    const float* fc1_w  = (const float*)d_in[13];
    const float* fc1_b  = (const float*)d_in[14];
    const float* fc2_w  = (const float*)d_in[15];
    const float* fc2_b  = (const float*)d_in[16];
    const int*   rpi    = (const int*)d_in[17];

    char* ws = (char*)d_ws;
    bf16* xn    = (bf16*)(ws + 0);          // [32768][192] = xn (16384) + yn (16384)
    bf16* yn    = (bf16*)(ws + 6291456);
    bf16* qbuf  = (bf16*)(ws + 12582912);   // [16384][192]
    bf16* kvbuf = (bf16*)(ws + 18874368);   // [16384][384]
    bf16* obuf  = (bf16*)(ws + 31457280);   // [16384][192]
    float* xo   = (float*)(ws + 37748736);  // [16384][180] fp32
    bf16* biast = (bf16*)(ws + 49545216);   // [6][256][576]
    bf16* wkv   = (bf16*)(ws + 51314688);
    bf16* wq    = (bf16*)(ws + 51462144);
    bf16* wproj = (bf16*)(ws + 51560448);
    bf16* wfc1  = (bf16*)(ws + 51658752);
    bf16* wfc2  = (bf16*)(ws + 51953664);
    bf16* hmid  = (bf16*)(ws + 6291456);    // reuse yn/qbuf/kvbuf region
    bf16* xn2   = xn;                       // xn dead after gemm_kvq

    prep_kernel<<<5440, 256, 0, stream>>>(kv_w, q_w, proj_w, fc1_w, fc2_w, rpb, rpi,
                                          wkv, wq, wproj, wfc1, wfc2, biast);
    ln_kernel<<<8192, 256, 0, stream>>>(x, y, n1g, n1b, xn);
    gemm_kvq<<<dim3(128, 9), 256, 0, stream>>>(xn, yn, wkv, wq, kv_b, q_b, kvbuf, qbuf);
    attn_kernel<<<768, 512, 0, stream>>>(qbuf, kvbuf, biast, obuf);
    gemm_ep<2, 4, 192, 180, 180, 2><<<dim3(128, 3), 256, 0, stream>>>(obuf, wproj, proj_b, x, xo);
    ln_kernel<<<4096, 256, 0, stream>>>(xo, xo, n2g, n2b, xn2);
    gemm_ep<4, 3, 192, 720, 736, 3><<<dim3(64, 12), 256, 0, stream>>>(xn2, wfc1, fc1_b, nullptr, hmid);
    gemm_ep<2, 4, 736, 180, 180, 2><<<dim3(128, 3), 256, 0, stream>>>(hmid, wfc2, fc2_b, xo, (float*)d_out);
}